// Round 2
// baseline (247.955 us; speedup 1.0000x reference)
//
#include <hip/hip_runtime.h>

#define BATCH 512
#define GRID_N 25
#define NODES 625            // 25*25
#define BN (BATCH * NODES)   // 320000
#define F 66
#define D 64

// Bitcast-safe wave broadcast: v_readlane_b32 (builtin is int-typed; passing
// float would do a NUMERIC float->int conversion — that was round 1's bug).
__device__ __forceinline__ float lane_bcast(float v, int l) {
    return __uint_as_float(__builtin_amdgcn_readlane(__float_as_uint(v), l));
}

// ---------------- Kernel A: h = x @ Wfc^T + bfc ; u = h.Wat[0:64], v = h.Wat[64:128]
// one wave per node; lane owns output channel d = lane
__global__ __launch_bounds__(256) void fc_kernel(
    const float* __restrict__ x, const float* __restrict__ Wfc,
    const float* __restrict__ bfc, const float* __restrict__ Wat,
    float* __restrict__ hout, float* __restrict__ u, float* __restrict__ v)
{
    const int lane = threadIdx.x & 63;
    const int gw   = (blockIdx.x * blockDim.x + threadIdx.x) >> 6;
    const int nw   = (gridDim.x * blockDim.x) >> 6;

    // per-lane FC weight row (66 VGPRs), loaded once per wave
    float w[F];
#pragma unroll
    for (int f = 0; f < F; ++f) w[f] = Wfc[lane * F + f];
    const float bf  = bfc[lane];
    const float wa1 = Wat[lane];
    const float wa2 = Wat[64 + lane];

    for (int bn = gw; bn < BN; bn += nw) {
        const float* xr = x + (size_t)bn * F;
        const float xa = xr[lane];
        const float xb = (lane < 2) ? xr[64 + lane] : 0.0f;

        float acc = 0.0f;
#pragma unroll
        for (int f = 0; f < 64; ++f) {
            const float xf = lane_bcast(xa, f);   // SGPR broadcast of x[bn][f]
            acc = fmaf(xf, w[f], acc);            // v_fmac_f32 v, s, v
        }
        acc = fmaf(lane_bcast(xb, 0), w[64], acc);
        acc = fmaf(lane_bcast(xb, 1), w[65], acc);

        const float h = acc + bf;
        hout[(size_t)bn * D + lane] = h;   // attn_vector == h (softmax row-sum == 1)

        float up = h * wa1;
        float vp = h * wa2;
#pragma unroll
        for (int off = 32; off > 0; off >>= 1) {
            up += __shfl_xor(up, off, 64);
            vp += __shfl_xor(vp, off, 64);
        }
        if (lane == 0) { u[bn] = up; v[bn] = vp; }
    }
}

// ---------------- Kernel B: s[k] = leaky(u[n] + v[neigh(n,k)] + b_at); softmax over k
__global__ __launch_bounds__(256) void attn_kernel(
    const float* __restrict__ u, const float* __restrict__ v,
    const float* __restrict__ bat, float* __restrict__ wout)
{
    const int bn = blockIdx.x * blockDim.x + threadIdx.x;
    if (bn >= BN) return;

    const int b   = bn / NODES;
    const int n   = bn - b * NODES;
    const int row = n / GRID_N;
    const int col = n - row * GRID_N;
    // reference's edge clamp: shift whole 3x3 window inward at the borders
    const int r0 = row + (row == 0) - (row == GRID_N - 1);
    const int c0 = col + (col == 0) - (col == GRID_N - 1);

    const float* vb = v + b * NODES;
    const float u0 = u[bn] + bat[0];

    float s[9];
#pragma unroll
    for (int k = 0; k < 9; ++k) {
        const int nr = r0 + (k / 3) - 1;
        const int nc = c0 + (k % 3) - 1;
        const float t = u0 + vb[nr * GRID_N + nc];
        s[k] = (t >= 0.0f) ? t : 0.01f * t;
    }
    float m = s[0];
#pragma unroll
    for (int k = 1; k < 9; ++k) m = fmaxf(m, s[k]);
    float sum = 0.0f;
#pragma unroll
    for (int k = 0; k < 9; ++k) { s[k] = __expf(s[k] - m); sum += s[k]; }
    const float inv = 1.0f / sum;
#pragma unroll
    for (int k = 0; k < 9; ++k) wout[(size_t)bn * 9 + k] = s[k] * inv;
}

extern "C" void kernel_launch(void* const* d_in, const int* in_sizes, int n_in,
                              void* d_out, int out_size, void* d_ws, size_t ws_size,
                              hipStream_t stream)
{
    const float* x   = (const float*)d_in[0];
    const float* Wfc = (const float*)d_in[1];
    const float* bfc = (const float*)d_in[2];
    const float* Wat = (const float*)d_in[3];
    const float* bat = (const float*)d_in[4];

    float* hout = (float*)d_out;                       // [B, N, 64]
    float* wout = (float*)d_out + (size_t)BN * D;      // [B, N, 9]
    float* u = (float*)d_ws;                           // [B*N]
    float* v = u + BN;                                 // [B*N]

    fc_kernel<<<4096, 256, 0, stream>>>(x, Wfc, bfc, Wat, hout, u, v);
    attn_kernel<<<(BN + 255) / 256, 256, 0, stream>>>(u, v, bat, wout);
}

// Round 3
// 177.251 us; speedup vs baseline: 1.3989x; 1.3989x over previous
//
#include <hip/hip_runtime.h>

#define BATCH 512
#define GRID_N 25
#define NODES 625            // 25*25
#define BN (BATCH * NODES)   // 320000
#define NTILES (BN / 16)     // 20000
#define F 66
#define D 64

typedef short bf16x8 __attribute__((ext_vector_type(8)));  // 8 bf16 bits (4 VGPRs)
typedef float f32x4  __attribute__((ext_vector_type(4)));

// fp32 -> bf16 bits, round-to-nearest-even
__device__ __forceinline__ short f2bf(float f) {
    union { float f; unsigned u; } c; c.f = f;
    unsigned r = c.u + 0x7fffu + ((c.u >> 16) & 1u);
    return (short)(r >> 16);
}

// ---------------- Kernel A (MFMA): h = x @ Wfc^T + bfc ; u = h.Wat[0:64], v = h.Wat[64:128]
// One wave per 16-node tile. A[m=lane&15][k=quad*8+j], B[k][n=lane&15] = Wfc[n][k],
// C/D: row = quad*4+reg, col = lane&15  (guide §3, m89-verified layouts).
__global__ __launch_bounds__(256, 4) void fc_mfma(
    const float* __restrict__ x, const float* __restrict__ Wfc,
    const float* __restrict__ bfc, const float* __restrict__ Wat,
    float* __restrict__ hout, float* __restrict__ u, float* __restrict__ v)
{
    const int lane = threadIdx.x & 63;
    const int l15  = lane & 15;
    const int quad = lane >> 4;
    const int gw   = (blockIdx.x * blockDim.x + threadIdx.x) >> 6;
    const int nw   = (gridDim.x * blockDim.x) >> 6;

    // ---- per-wave constants (loaded once) ----
    // B fragments: lane holds Wfc[n][k], n = t*16+l15, k = c*32 + quad*8 + j
    bf16x8 bfrag[4][3];
#pragma unroll
    for (int t = 0; t < 4; ++t) {
        const float* wr = Wfc + (t * 16 + l15) * F;
#pragma unroll
        for (int c = 0; c < 2; ++c) {
            bf16x8 fr;
#pragma unroll
            for (int j = 0; j < 8; ++j) fr[j] = f2bf(wr[c * 32 + quad * 8 + j]);
            bfrag[t][c] = fr;
        }
        bf16x8 z = {0, 0, 0, 0, 0, 0, 0, 0};          // K-chunk 2: only k=64,65 live
        if (quad == 0) { z[0] = f2bf(wr[64]); z[1] = f2bf(wr[65]); }
        bfrag[t][2] = z;
    }
    float bft[4], wa1[4], wa2[4];
#pragma unroll
    for (int t = 0; t < 4; ++t) {
        bft[t] = bfc[t * 16 + l15];
        wa1[t] = Wat[t * 16 + l15];
        wa2[t] = Wat[64 + t * 16 + l15];
    }

    for (int tile = gw; tile < NTILES; tile += nw) {
        const int bn0 = tile * 16;
        const float* xr = x + (size_t)(bn0 + l15) * F;   // A row m = l15

        // ---- A fragments (8 contiguous floats of the row per chunk) ----
        bf16x8 afrag[3];
#pragma unroll
        for (int c = 0; c < 2; ++c) {
            bf16x8 fr;
#pragma unroll
            for (int j = 0; j < 8; ++j) fr[j] = f2bf(xr[c * 32 + quad * 8 + j]);
            afrag[c] = fr;
        }
        {
            bf16x8 z = {0, 0, 0, 0, 0, 0, 0, 0};
            if (quad == 0) { z[0] = f2bf(xr[64]); z[1] = f2bf(xr[65]); }
            afrag[2] = z;
        }

        // ---- MFMA: 4 N-tiles x 3 K-chunks ----
        f32x4 acc[4] = {{0,0,0,0},{0,0,0,0},{0,0,0,0},{0,0,0,0}};
#pragma unroll
        for (int t = 0; t < 4; ++t)
#pragma unroll
            for (int c = 0; c < 3; ++c)
                acc[t] = __builtin_amdgcn_mfma_f32_16x16x32_bf16(afrag[c], bfrag[t][c], acc[t], 0, 0, 0);

        // ---- epilogue: h store + u/v dots ----
        float pu[4] = {0, 0, 0, 0}, pv[4] = {0, 0, 0, 0};
#pragma unroll
        for (int t = 0; t < 4; ++t) {
#pragma unroll
            for (int r = 0; r < 4; ++r) {
                const float h = acc[t][r] + bft[t];
                hout[(size_t)(bn0 + quad * 4 + r) * D + t * 16 + l15] = h;
                pu[r] = fmaf(h, wa1[t], pu[r]);
                pv[r] = fmaf(h, wa2[t], pv[r]);
            }
        }
        // reduce across the 16 lanes of this quad (xor of low 4 bits stays in-group)
#pragma unroll
        for (int off = 8; off > 0; off >>= 1) {
#pragma unroll
            for (int r = 0; r < 4; ++r) {
                pu[r] += __shfl_xor(pu[r], off, 64);
                pv[r] += __shfl_xor(pv[r], off, 64);
            }
        }
        if (l15 == 0) {
#pragma unroll
            for (int r = 0; r < 4; ++r) {
                u[bn0 + quad * 4 + r] = pu[r];
                v[bn0 + quad * 4 + r] = pv[r];
            }
        }
    }
}

// ---------------- Kernel B: s[k] = leaky(u[n] + v[neigh(n,k)] + b_at); softmax over k
__global__ __launch_bounds__(256) void attn_kernel(
    const float* __restrict__ u, const float* __restrict__ v,
    const float* __restrict__ bat, float* __restrict__ wout)
{
    const int bn = blockIdx.x * blockDim.x + threadIdx.x;
    if (bn >= BN) return;

    const int b   = bn / NODES;
    const int n   = bn - b * NODES;
    const int row = n / GRID_N;
    const int col = n - row * GRID_N;
    // reference's edge clamp: shift whole 3x3 window inward at the borders
    const int r0 = row + (row == 0) - (row == GRID_N - 1);
    const int c0 = col + (col == 0) - (col == GRID_N - 1);

    const float* vb = v + b * NODES;
    const float u0 = u[bn] + bat[0];

    float s[9];
#pragma unroll
    for (int k = 0; k < 9; ++k) {
        const int nr = r0 + (k / 3) - 1;
        const int nc = c0 + (k % 3) - 1;
        const float t = u0 + vb[nr * GRID_N + nc];
        s[k] = (t >= 0.0f) ? t : 0.01f * t;
    }
    float m = s[0];
#pragma unroll
    for (int k = 1; k < 9; ++k) m = fmaxf(m, s[k]);
    float sum = 0.0f;
#pragma unroll
    for (int k = 0; k < 9; ++k) { s[k] = __expf(s[k] - m); sum += s[k]; }
    const float inv = 1.0f / sum;
#pragma unroll
    for (int k = 0; k < 9; ++k) wout[(size_t)bn * 9 + k] = s[k] * inv;
}

extern "C" void kernel_launch(void* const* d_in, const int* in_sizes, int n_in,
                              void* d_out, int out_size, void* d_ws, size_t ws_size,
                              hipStream_t stream)
{
    const float* x   = (const float*)d_in[0];
    const float* Wfc = (const float*)d_in[1];
    const float* bfc = (const float*)d_in[2];
    const float* Wat = (const float*)d_in[3];
    const float* bat = (const float*)d_in[4];

    float* hout = (float*)d_out;                       // [B, N, 64]
    float* wout = (float*)d_out + (size_t)BN * D;      // [B, N, 9]
    float* u = (float*)d_ws;                           // [B*N]
    float* v = u + BN;                                 // [B*N]

    // 1000 blocks x 4 waves = 4000 waves, 5 tiles each (20000 total, exact)
    fc_mfma<<<1000, 256, 0, stream>>>(x, Wfc, bfc, Wat, hout, u, v);
    attn_kernel<<<(BN + 255) / 256, 256, 0, stream>>>(u, v, bat, wout);
}